// Round 4
// baseline (15554.480 us; speedup 1.0000x reference)
//
#include <hip/hip_runtime.h>
#include <hip/hip_bf16.h>
#include <math.h>

#define TSEQ 4096
#define EMBD 1024
#define HH   512
#define NTAGS 5
#define NGATE 2048
#define NCONS 32
#define NEGV (-10000.0f)
#define START_TAG 3
#define STOP_TAG 4

typedef unsigned long long u64;
typedef unsigned int u32;

__device__ __forceinline__ float sigm(float x){ return 1.0f/(1.0f+expf(-x)); }

__device__ __forceinline__ u64 pack_pair(float h, u32 tag){
  return ((u64)tag << 32) | (u64)__float_as_uint(h);
}

// ---------------- init: prime all mailboxes (parity0 = h0 tag 0, parity1 invalid) --
// mbox layout: [dir][parity][consumer][512] u64 pairs
__global__ void k_init(const float* __restrict__ h0, u64* __restrict__ mbox){
  int idx = blockIdx.x*256 + threadIdx.x;
  if (idx < 2*2*NCONS*HH){
    int u    = idx & 511;
    int rest = idx >> 9;        // 0..127
    int c    = rest & 31;
    int dp   = rest >> 5;       // 0..3
    int dir  = dp >> 1, par = dp & 1;
    u64 val = par ? pack_pair(0.f, 0xFFFFFFFFu) : pack_pair(h0[dir*HH + u], 0u);
    mbox[(((size_t)(dir*2 + par))*NCONS + c)*HH + u] = val;
  }
}

// ---------------- input projection GEMM (fp32, fused embedding gather + bias) ----
// A[dir][t][n] = sum_k W_ih[n][k] * emb[sent[t]][k] + b[n]
__global__ __launch_bounds__(256) void k_inproj(
    const int* __restrict__ sent, const float* __restrict__ emb,
    const float* __restrict__ Wf, const float* __restrict__ bf,
    const float* __restrict__ Wb, const float* __restrict__ bb,
    float* __restrict__ A){
  __shared__ __align__(16) float As[16][132];
  __shared__ __align__(16) float Bs[16][132];
  __shared__ int srow[128];
  const int tid = threadIdx.x;
  const int t0  = blockIdx.x * 128;
  const int ng0 = blockIdx.y * 128;
  const int dir = (ng0 >= NGATE) ? 1 : 0;
  const float* __restrict__ W    = dir ? Wb : Wf;
  const float* __restrict__ bias = dir ? bb : bf;
  const int n0 = ng0 & (NGATE - 1);
  if (tid < 128) srow[tid] = sent[t0 + tid];
  __syncthreads();
  const int lr = tid >> 2;          // loader row 0..63 (two passes)
  const int kq = (tid & 3) * 4;     // k sub-offset within 16
  const float* ea0 = emb + (size_t)srow[lr]      * EMBD + kq;
  const float* ea1 = emb + (size_t)srow[lr + 64] * EMBD + kq;
  const float* wb0 = W + (size_t)(n0 + lr)      * EMBD + kq;
  const float* wb1 = W + (size_t)(n0 + lr + 64) * EMBD + kq;
  const int tx = tid & 15, ty = tid >> 4;
  float acc[8][8];
  #pragma unroll
  for (int i = 0; i < 8; i++)
    #pragma unroll
    for (int j = 0; j < 8; j++) acc[i][j] = 0.f;

  for (int k0 = 0; k0 < EMBD; k0 += 16){
    float4 va0 = *(const float4*)(ea0 + k0);
    float4 va1 = *(const float4*)(ea1 + k0);
    float4 vb0 = *(const float4*)(wb0 + k0);
    float4 vb1 = *(const float4*)(wb1 + k0);
    As[kq+0][lr] = va0.x; As[kq+1][lr] = va0.y; As[kq+2][lr] = va0.z; As[kq+3][lr] = va0.w;
    As[kq+0][lr+64] = va1.x; As[kq+1][lr+64] = va1.y; As[kq+2][lr+64] = va1.z; As[kq+3][lr+64] = va1.w;
    Bs[kq+0][lr] = vb0.x; Bs[kq+1][lr] = vb0.y; Bs[kq+2][lr] = vb0.z; Bs[kq+3][lr] = vb0.w;
    Bs[kq+0][lr+64] = vb1.x; Bs[kq+1][lr+64] = vb1.y; Bs[kq+2][lr+64] = vb1.z; Bs[kq+3][lr+64] = vb1.w;
    __syncthreads();
    #pragma unroll
    for (int k = 0; k < 16; k++){
      float a[8], b[8];
      *(float4*)&a[0] = *(const float4*)&As[k][ty*8];
      *(float4*)&a[4] = *(const float4*)&As[k][ty*8 + 4];
      #pragma unroll
      for (int j = 0; j < 8; j++) b[j] = Bs[k][tx + 16*j];
      #pragma unroll
      for (int i = 0; i < 8; i++)
        #pragma unroll
        for (int j = 0; j < 8; j++)
          acc[i][j] = fmaf(a[i], b[j], acc[i][j]);
    }
    __syncthreads();
  }
  float bj[8];
  #pragma unroll
  for (int j = 0; j < 8; j++) bj[j] = bias[n0 + tx + 16*j];
  float* Abase = A + (size_t)dir * TSEQ * NGATE;
  #pragma unroll
  for (int i = 0; i < 8; i++){
    float* dst = Abase + (size_t)(t0 + ty*8 + i) * NGATE + n0 + tx;
    #pragma unroll
    for (int j = 0; j < 8; j++) dst[16*j] = acc[i][j] + bj[j];
  }
}

// ---------------- persistent BiLSTM recurrence ----------------
// 64 WGs x 512 thr: 32 WGs/dir, 16 units/WG. Thread map: ul = tid>>5 (unit),
// g = (tid>>3)&3 (gate), q = tid&7 (col octant); each unit's 32 lanes form one
// half-wave (in-wave reduce + parallel transcendentals).
// h exchange: PUSH fan-out to per-consumer private mailboxes of (tag,value)
// u64 pairs. Producer: publisher's h2 is shfl-broadcast to its 32-lane group,
// lane k stores to mailbox k (1 store inst/wave). Consumer: wave 0 polls its
// OWN 4KB mailbox (single reader per line -> no cross-wave queueing), masked
// per-element reload, decodes into double-buffered LDS; 1 barrier/step.
__global__ __launch_bounds__(512) void k_lstm(
    const float* __restrict__ Whf, const float* __restrict__ Whb,
    const float* __restrict__ c0,
    const float* __restrict__ A, float* __restrict__ hseq,
    u64* __restrict__ mbox){
  const int bid  = blockIdx.x;
  const int dir  = bid >> 5;
  const int wg   = bid & 31;
  const int tid  = threadIdx.x;
  const int lane = tid & 63;
  const int ul   = tid >> 5;        // unit local 0..15
  const int g    = (tid >> 3) & 3;  // gate i,f,g,o
  const int q    = tid & 7;         // column octant
  const int unit = wg*16 + ul;
  const float* __restrict__ Wh = dir ? Whb : Whf;

  float wreg[64];                   // Wh[g*512+unit][q*64 .. q*64+63]
  {
    const float* wr = Wh + (size_t)(g*HH + unit)*HH + q*64;
    #pragma unroll
    for (int j4 = 0; j4 < 16; j4++){
      float4 vv = *(const float4*)(wr + 4*j4);
      wreg[4*j4+0]=vv.x; wreg[4*j4+1]=vv.y; wreg[4*j4+2]=vv.z; wreg[4*j4+3]=vv.w;
    }
  }
  float creg = 0.f;
  if (g == 0 && q == 0) creg = c0[dir*HH + unit];

  __shared__ __align__(16) float hl[2][8*68];   // [buf][j*68 + c], pad->bank-rotate
  u64* mb = mbox + (size_t)dir*2*NCONS*HH;
  const float* __restrict__ Ab = A + (size_t)dir*TSEQ*NGATE;

  for (int s = 0; s < TSEQ; s++){
    const int t = dir ? (TSEQ - 1 - s) : s;
    // prefetch input-projection value for this thread's gate row (q==0 lanes)
    float av = 0.f;
    if (q == 0) av = Ab[(size_t)t*NGATE + g*HH + unit];

    if (tid < 64){                   // wave 0: poll own mailbox + stage
      u64* src = mb + ((size_t)(s & 1)*NCONS + wg)*HH;
      u64 v[8];
      #pragma unroll
      for (int j = 0; j < 8; j++)
        v[j] = __hip_atomic_load(&src[j*64 + lane], __ATOMIC_RELAXED, __HIP_MEMORY_SCOPE_AGENT);
      unsigned need = 0xFFu;
      while (true){
        #pragma unroll
        for (int j = 0; j < 8; j++)
          if (((need >> j) & 1u) && ((u32)(v[j] >> 32) == (u32)s)) need &= ~(1u << j);
        if (__all(need == 0u)) break;
        #pragma unroll
        for (int j = 0; j < 8; j++)
          if ((need >> j) & 1u)
            v[j] = __hip_atomic_load(&src[j*64 + lane], __ATOMIC_RELAXED, __HIP_MEMORY_SCOPE_AGENT);
      }
      float* hb = hl[s & 1];
      #pragma unroll
      for (int j = 0; j < 8; j++) hb[j*68 + lane] = __uint_as_float((u32)v[j]);
    }
    __syncthreads();

    // matvec: 64 FMAs from LDS chunk q
    const float* hq = hl[s & 1] + q*68;
    float p0 = 0.f, p1 = 0.f, p2 = 0.f, p3 = 0.f;
    #pragma unroll
    for (int j4 = 0; j4 < 16; j4++){
      float4 h4 = *(const float4*)(hq + 4*j4);
      p0 = fmaf(wreg[4*j4+0], h4.x, p0);
      p1 = fmaf(wreg[4*j4+1], h4.y, p1);
      p2 = fmaf(wreg[4*j4+2], h4.z, p2);
      p3 = fmaf(wreg[4*j4+3], h4.w, p3);
    }
    float acc = ((p0 + p1) + (p2 + p3)) + av;
    acc += __shfl_xor(acc, 1);
    acc += __shfl_xor(acc, 2);
    acc += __shfl_xor(acc, 4);
    // parallel nonlinearity: one transcendental per gate lane
    const float act = (g == 2) ? tanhf(acc) : sigm(acc);
    const float f_ = __shfl_down(act, 8);
    const float g_ = __shfl_down(act, 16);
    const float o_ = __shfl_down(act, 24);
    float h2v = 0.f;
    if (g == 0 && q == 0){
      const float c2 = f_*creg + act*g_;
      h2v = o_*tanhf(c2);
      creg = c2;
    }
    // broadcast h2 to the unit's 32-lane group, fan-out: lane k -> mailbox k
    h2v = __shfl(h2v, tid & 32);
    {
      const int c32 = tid & 31;
      u64* dst = mb + ((size_t)((s + 1) & 1)*NCONS + c32)*HH + unit;
      __hip_atomic_store(dst, pack_pair(h2v, (u32)(s + 1)),
                         __ATOMIC_RELAXED, __HIP_MEMORY_SCOPE_AGENT);
    }
    if (g == 0 && q == 0)
      hseq[((size_t)dir*TSEQ + t)*HH + unit] = h2v;
  }
}

// ---------------- emission features: feats[t][n] = lstm_out[t] . W_out[n] + b ----
__global__ __launch_bounds__(64) void k_feats(
    const float* __restrict__ Wout, const float* __restrict__ bout,
    const float* __restrict__ hseq, float* __restrict__ feats){
  const int t = blockIdx.x, lane = threadIdx.x;
  const float* hf = hseq + (size_t)t*HH;
  const float* hb = hseq + (size_t)(TSEQ + t)*HH;
  float x[16];
  #pragma unroll
  for (int k = 0; k < 8; k++) x[k]     = hf[lane + 64*k];
  #pragma unroll
  for (int k = 0; k < 8; k++) x[8 + k] = hb[lane + 64*k];
  #pragma unroll
  for (int n = 0; n < NTAGS; n++){
    const float* wr = Wout + (size_t)n*(2*HH);
    float p = 0.f;
    #pragma unroll
    for (int k = 0; k < 8; k++) p = fmaf(x[k],     wr[lane + 64*k],      p);
    #pragma unroll
    for (int k = 0; k < 8; k++) p = fmaf(x[8 + k], wr[HH + lane + 64*k], p);
    #pragma unroll
    for (int d = 1; d < 64; d <<= 1) p += __shfl_xor(p, d);
    if (lane == 0) feats[t*8 + n] = p + bout[n];
  }
}

// ---------------- Viterbi forward + backtrack (1 wave) ----------------
// lane = to*8 + from (5x5 valid). First-max tie-break matches jnp.argmax.
__global__ __launch_bounds__(64) void k_viterbi(
    const float* __restrict__ trans, const float* __restrict__ feats,
    int* __restrict__ bpw, float* __restrict__ out){
  const int lane = threadIdx.x;
  const int to = lane >> 3, from = lane & 7;
  const bool v_to = (to < NTAGS), v_from = (from < NTAGS);
  const float tv = (v_to && v_from) ? trans[to*NTAGS + from] : -1e30f;
  float fv = (from == START_TAG) ? 0.f : NEGV;    // fv for my 'from' tag
  __shared__ float fsh[512];
  for (int t0 = 0; t0 < TSEQ; t0 += 64){
    __syncthreads();
    #pragma unroll
    for (int i = 0; i < 8; i++) fsh[lane + 64*i] = feats[t0*8 + lane + 64*i];
    __syncthreads();
    for (int i = 0; i < 64; i++){
      const int t = t0 + i;
      float bv = fv + tv; int bi = from;
      #pragma unroll
      for (int d = 1; d < 8; d <<= 1){
        float ov = __shfl_xor(bv, d);
        int   oi = __shfl_xor(bi, d);
        if (ov > bv || (ov == bv && oi < bi)){ bv = ov; bi = oi; }
      }
      float nf = bv + fsh[i*8 + to];       // new fv[to] (garbage for to>=5, discarded)
      int wv = 0;
      #pragma unroll
      for (int tt = 0; tt < 5; tt++) wv |= (__shfl(bi, tt*8) & 15) << (4*tt);
      if (lane == 0) bpw[t] = wv;
      float nfv = __shfl(nf, from*8);
      fv = v_from ? nfv : NEGV;
    }
  }
  // terminal: fv + trans[STOP][from]
  float bv = fv + (v_from ? trans[STOP_TAG*NTAGS + from] : -1e30f);
  int bi = from;
  #pragma unroll
  for (int d = 1; d < 8; d <<= 1){
    float ov = __shfl_xor(bv, d);
    int   oi = __shfl_xor(bi, d);
    if (ov > bv || (ov == bv && oi < bi)){ bv = ov; bi = oi; }
  }
  float score = __shfl(bv, 0);
  int btag = __shfl(bi, 0);
  if (lane == 0){ out[0] = score; out[TSEQ] = (float)btag; }   // out[1 + (T-1)]
  int tag = btag;
  for (int b = 63; b >= 0; b--){
    int v = bpw[b*64 + lane];
    for (int i = 63; i >= 0; i--){
      int t = b*64 + i;
      if (t == 0) break;                     // bpw[0] points at virtual START
      int wv2 = __shfl(v, i);
      int prev = (wv2 >> (tag*4)) & 15;
      if (lane == 0) out[t] = (float)prev;   // out[1 + (t-1)]
      tag = prev;
    }
  }
}

extern "C" void kernel_launch(void* const* d_in, const int* in_sizes, int n_in,
                              void* d_out, int out_size, void* d_ws, size_t ws_size,
                              hipStream_t stream) {
  const int*   sent = (const int*)  d_in[0];
  const float* emb  = (const float*)d_in[1];
  const float* Wihf = (const float*)d_in[2];
  const float* Whhf = (const float*)d_in[3];
  const float* bf_  = (const float*)d_in[4];
  const float* Wihb = (const float*)d_in[5];
  const float* Whhb = (const float*)d_in[6];
  const float* bb_  = (const float*)d_in[7];
  const float* Wout = (const float*)d_in[8];
  const float* bout = (const float*)d_in[9];
  const float* trans= (const float*)d_in[10];
  const float* h0   = (const float*)d_in[11];
  const float* c0   = (const float*)d_in[12];
  float* out = (float*)d_out;

  float* ws   = (float*)d_ws;
  float* A    = ws;                                  // [2][T][2048]
  float* hseq = A    + (size_t)2*TSEQ*NGATE;         // [2][T][512]
  u64*   mbox = (u64*)(hseq + (size_t)2*TSEQ*HH);    // [2][2][32][512] (tag,val)
  float* fe   = (float*)(mbox + (size_t)2*2*NCONS*HH); // [T][8]
  int*   bpw  = (int*)(fe + (size_t)TSEQ*8);         // [T] packed nibbles
  (void)ws_size;

  k_init<<<(2*2*NCONS*HH + 255)/256, 256, 0, stream>>>(h0, mbox);
  dim3 gg(TSEQ/128, 4096/128);
  k_inproj<<<gg, 256, 0, stream>>>(sent, emb, Wihf, bf_, Wihb, bb_, A);
  k_lstm<<<64, 512, 0, stream>>>(Whhf, Whhb, c0, A, hseq, mbox);
  k_feats<<<TSEQ, 64, 0, stream>>>(Wout, bout, hseq, fe);
  k_viterbi<<<1, 64, 0, stream>>>(trans, fe, bpw, out);
}

// Round 5
// 15305.598 us; speedup vs baseline: 1.0163x; 1.0163x over previous
//
#include <hip/hip_runtime.h>
#include <hip/hip_bf16.h>
#include <math.h>

#define TSEQ 4096
#define EMBD 1024
#define HH   512
#define NTAGS 5
#define NGATE 2048
#define NREP 8
#define NEGV (-10000.0f)
#define START_TAG 3
#define STOP_TAG 4

typedef unsigned long long u64;
typedef unsigned int u32;

__device__ __forceinline__ float sigm(float x){ return 1.0f/(1.0f+expf(-x)); }

__device__ __forceinline__ u64 pack_pair(float h, u32 tag){
  return ((u64)tag << 32) | (u64)__float_as_uint(h);
}

// ---------------- init: prime replicated pair buffers ----------------
// mbox layout: [dir][parity][replica][512] u64 pairs
__global__ void k_init(const float* __restrict__ h0, u64* __restrict__ mbox){
  int idx = blockIdx.x*256 + threadIdx.x;
  if (idx < 2*2*NREP*HH){
    int u    = idx & 511;
    int rest = idx >> 9;        // 0..31
    int rep  = rest & 7;
    int dp   = rest >> 3;       // 0..3
    int par  = dp & 1, dir = dp >> 1;
    u64 val = par ? pack_pair(0.f, 0xFFFFFFFFu) : pack_pair(h0[dir*HH + u], 0u);
    mbox[(((size_t)(dir*2 + par))*NREP + rep)*HH + u] = val;
  }
}

// ---------------- input projection GEMM (fp32, fused embedding gather + bias) ----
// A[dir][t][n] = sum_k W_ih[n][k] * emb[sent[t]][k] + b[n]
__global__ __launch_bounds__(256) void k_inproj(
    const int* __restrict__ sent, const float* __restrict__ emb,
    const float* __restrict__ Wf, const float* __restrict__ bf,
    const float* __restrict__ Wb, const float* __restrict__ bb,
    float* __restrict__ A){
  __shared__ __align__(16) float As[16][132];
  __shared__ __align__(16) float Bs[16][132];
  __shared__ int srow[128];
  const int tid = threadIdx.x;
  const int t0  = blockIdx.x * 128;
  const int ng0 = blockIdx.y * 128;
  const int dir = (ng0 >= NGATE) ? 1 : 0;
  const float* __restrict__ W    = dir ? Wb : Wf;
  const float* __restrict__ bias = dir ? bb : bf;
  const int n0 = ng0 & (NGATE - 1);
  if (tid < 128) srow[tid] = sent[t0 + tid];
  __syncthreads();
  const int lr = tid >> 2;          // loader row 0..63 (two passes)
  const int kq = (tid & 3) * 4;     // k sub-offset within 16
  const float* ea0 = emb + (size_t)srow[lr]      * EMBD + kq;
  const float* ea1 = emb + (size_t)srow[lr + 64] * EMBD + kq;
  const float* wb0 = W + (size_t)(n0 + lr)      * EMBD + kq;
  const float* wb1 = W + (size_t)(n0 + lr + 64) * EMBD + kq;
  const int tx = tid & 15, ty = tid >> 4;
  float acc[8][8];
  #pragma unroll
  for (int i = 0; i < 8; i++)
    #pragma unroll
    for (int j = 0; j < 8; j++) acc[i][j] = 0.f;

  for (int k0 = 0; k0 < EMBD; k0 += 16){
    float4 va0 = *(const float4*)(ea0 + k0);
    float4 va1 = *(const float4*)(ea1 + k0);
    float4 vb0 = *(const float4*)(wb0 + k0);
    float4 vb1 = *(const float4*)(wb1 + k0);
    As[kq+0][lr] = va0.x; As[kq+1][lr] = va0.y; As[kq+2][lr] = va0.z; As[kq+3][lr] = va0.w;
    As[kq+0][lr+64] = va1.x; As[kq+1][lr+64] = va1.y; As[kq+2][lr+64] = va1.z; As[kq+3][lr+64] = va1.w;
    Bs[kq+0][lr] = vb0.x; Bs[kq+1][lr] = vb0.y; Bs[kq+2][lr] = vb0.z; Bs[kq+3][lr] = vb0.w;
    Bs[kq+0][lr+64] = vb1.x; Bs[kq+1][lr+64] = vb1.y; Bs[kq+2][lr+64] = vb1.z; Bs[kq+3][lr+64] = vb1.w;
    __syncthreads();
    #pragma unroll
    for (int k = 0; k < 16; k++){
      float a[8], b[8];
      *(float4*)&a[0] = *(const float4*)&As[k][ty*8];
      *(float4*)&a[4] = *(const float4*)&As[k][ty*8 + 4];
      #pragma unroll
      for (int j = 0; j < 8; j++) b[j] = Bs[k][tx + 16*j];
      #pragma unroll
      for (int i = 0; i < 8; i++)
        #pragma unroll
        for (int j = 0; j < 8; j++)
          acc[i][j] = fmaf(a[i], b[j], acc[i][j]);
    }
    __syncthreads();
  }
  float bj[8];
  #pragma unroll
  for (int j = 0; j < 8; j++) bj[j] = bias[n0 + tx + 16*j];
  float* Abase = A + (size_t)dir * TSEQ * NGATE;
  #pragma unroll
  for (int i = 0; i < 8; i++){
    float* dst = Abase + (size_t)(t0 + ty*8 + i) * NGATE + n0 + tx;
    #pragma unroll
    for (int j = 0; j < 8; j++) dst[16*j] = acc[i][j] + bj[j];
  }
}

// ---------------- persistent BiLSTM recurrence ----------------
// 64 WGs x 512 thr: 32 WGs/dir, 16 units/WG. Thread map: ul = tid>>5 (unit),
// g = (tid>>3)&3 (gate), q = tid&7 (col octant); each unit's 32 lanes form one
// half-wave (in-wave reduce + parallel transcendentals).
// h exchange: shared pull of self-certifying (tag,value) u64 pairs, with 8
// REPLICAS of the buffer. Consumer wg polls replica (wg&7) -> only 4 readers
// per cache line (vs 32 unreplicated), attacking same-line reader
// serialization at the coherence point. Publishers store each pair to all 8
// replicas (fire-and-forget relaxed stores; each replica line has 1 writer).
__global__ __launch_bounds__(512) void k_lstm(
    const float* __restrict__ Whf, const float* __restrict__ Whb,
    const float* __restrict__ c0,
    const float* __restrict__ A, float* __restrict__ hseq,
    u64* __restrict__ mbox){
  const int bid  = blockIdx.x;
  const int dir  = bid >> 5;
  const int wg   = bid & 31;
  const int tid  = threadIdx.x;
  const int lane = tid & 63;
  const int ul   = tid >> 5;        // unit local 0..15
  const int g    = (tid >> 3) & 3;  // gate i,f,g,o
  const int q    = tid & 7;         // column octant
  const int unit = wg*16 + ul;
  const float* __restrict__ Wh = dir ? Whb : Whf;

  float wreg[64];                   // Wh[g*512+unit][q*64 .. q*64+63]
  {
    const float* wr = Wh + (size_t)(g*HH + unit)*HH + q*64;
    #pragma unroll
    for (int j4 = 0; j4 < 16; j4++){
      float4 vv = *(const float4*)(wr + 4*j4);
      wreg[4*j4+0]=vv.x; wreg[4*j4+1]=vv.y; wreg[4*j4+2]=vv.z; wreg[4*j4+3]=vv.w;
    }
  }
  float creg = 0.f;
  if (g == 0 && q == 0) creg = c0[dir*HH + unit];

  __shared__ __align__(16) float hl[2][8*68];   // [buf][j*68 + c], pad->bank-rotate
  u64* mb = mbox + (size_t)dir*2*NREP*HH;
  const float* __restrict__ Ab = A + (size_t)dir*TSEQ*NGATE;

  for (int s = 0; s < TSEQ; s++){
    const int t = dir ? (TSEQ - 1 - s) : s;
    // prefetch input-projection value for this thread's gate row (q==0 lanes)
    float av = 0.f;
    if (q == 0) av = Ab[(size_t)t*NGATE + g*HH + unit];

    if (tid < 64){                   // wave 0: poll own replica + stage
      u64* src = mb + ((size_t)(s & 1)*NREP + (wg & 7))*HH;
      u64 v[8];
      #pragma unroll
      for (int j = 0; j < 8; j++)
        v[j] = __hip_atomic_load(&src[j*64 + lane], __ATOMIC_RELAXED, __HIP_MEMORY_SCOPE_AGENT);
      unsigned need = 0xFFu;
      while (true){
        #pragma unroll
        for (int j = 0; j < 8; j++)
          if (((need >> j) & 1u) && ((u32)(v[j] >> 32) == (u32)s)) need &= ~(1u << j);
        if (__all(need == 0u)) break;
        #pragma unroll
        for (int j = 0; j < 8; j++)
          if ((need >> j) & 1u)
            v[j] = __hip_atomic_load(&src[j*64 + lane], __ATOMIC_RELAXED, __HIP_MEMORY_SCOPE_AGENT);
      }
      float* hb = hl[s & 1];
      #pragma unroll
      for (int j = 0; j < 8; j++) hb[j*68 + lane] = __uint_as_float((u32)v[j]);
    }
    __syncthreads();

    // matvec: 64 FMAs from LDS chunk q
    const float* hq = hl[s & 1] + q*68;
    float p0 = 0.f, p1 = 0.f, p2 = 0.f, p3 = 0.f;
    #pragma unroll
    for (int j4 = 0; j4 < 16; j4++){
      float4 h4 = *(const float4*)(hq + 4*j4);
      p0 = fmaf(wreg[4*j4+0], h4.x, p0);
      p1 = fmaf(wreg[4*j4+1], h4.y, p1);
      p2 = fmaf(wreg[4*j4+2], h4.z, p2);
      p3 = fmaf(wreg[4*j4+3], h4.w, p3);
    }
    float acc = ((p0 + p1) + (p2 + p3)) + av;
    acc += __shfl_xor(acc, 1);
    acc += __shfl_xor(acc, 2);
    acc += __shfl_xor(acc, 4);
    // parallel nonlinearity: one transcendental per gate lane
    const float act = (g == 2) ? tanhf(acc) : sigm(acc);
    const float f_ = __shfl_down(act, 8);
    const float g_ = __shfl_down(act, 16);
    const float o_ = __shfl_down(act, 24);
    if (g == 0 && q == 0){
      const float c2 = f_*creg + act*g_;
      const float h2 = o_*tanhf(c2);
      creg = c2;
      hseq[((size_t)dir*TSEQ + t)*HH + unit] = h2;
      const u64 pk = pack_pair(h2, (u32)(s + 1));
      u64* dst = mb + (size_t)((s + 1) & 1)*NREP*HH + unit;
      #pragma unroll
      for (int r = 0; r < NREP; r++)
        __hip_atomic_store(dst + (size_t)r*HH, pk,
                           __ATOMIC_RELAXED, __HIP_MEMORY_SCOPE_AGENT);
    }
  }
}

// ---------------- emission features: feats[t][n] = lstm_out[t] . W_out[n] + b ----
__global__ __launch_bounds__(64) void k_feats(
    const float* __restrict__ Wout, const float* __restrict__ bout,
    const float* __restrict__ hseq, float* __restrict__ feats){
  const int t = blockIdx.x, lane = threadIdx.x;
  const float* hf = hseq + (size_t)t*HH;
  const float* hb = hseq + (size_t)(TSEQ + t)*HH;
  float x[16];
  #pragma unroll
  for (int k = 0; k < 8; k++) x[k]     = hf[lane + 64*k];
  #pragma unroll
  for (int k = 0; k < 8; k++) x[8 + k] = hb[lane + 64*k];
  #pragma unroll
  for (int n = 0; n < NTAGS; n++){
    const float* wr = Wout + (size_t)n*(2*HH);
    float p = 0.f;
    #pragma unroll
    for (int k = 0; k < 8; k++) p = fmaf(x[k],     wr[lane + 64*k],      p);
    #pragma unroll
    for (int k = 0; k < 8; k++) p = fmaf(x[8 + k], wr[HH + lane + 64*k], p);
    #pragma unroll
    for (int d = 1; d < 64; d <<= 1) p += __shfl_xor(p, d);
    if (lane == 0) feats[t*8 + n] = p + bout[n];
  }
}

// ---------------- Viterbi forward + backtrack (1 wave) ----------------
// lane = to*8 + from (5x5 valid). First-max tie-break matches jnp.argmax.
__global__ __launch_bounds__(64) void k_viterbi(
    const float* __restrict__ trans, const float* __restrict__ feats,
    int* __restrict__ bpw, float* __restrict__ out){
  const int lane = threadIdx.x;
  const int to = lane >> 3, from = lane & 7;
  const bool v_to = (to < NTAGS), v_from = (from < NTAGS);
  const float tv = (v_to && v_from) ? trans[to*NTAGS + from] : -1e30f;
  float fv = (from == START_TAG) ? 0.f : NEGV;    // fv for my 'from' tag
  __shared__ float fsh[512];
  for (int t0 = 0; t0 < TSEQ; t0 += 64){
    __syncthreads();
    #pragma unroll
    for (int i = 0; i < 8; i++) fsh[lane + 64*i] = feats[t0*8 + lane + 64*i];
    __syncthreads();
    for (int i = 0; i < 64; i++){
      const int t = t0 + i;
      float bv = fv + tv; int bi = from;
      #pragma unroll
      for (int d = 1; d < 8; d <<= 1){
        float ov = __shfl_xor(bv, d);
        int   oi = __shfl_xor(bi, d);
        if (ov > bv || (ov == bv && oi < bi)){ bv = ov; bi = oi; }
      }
      float nf = bv + fsh[i*8 + to];       // new fv[to] (garbage for to>=5, discarded)
      int wv = 0;
      #pragma unroll
      for (int tt = 0; tt < 5; tt++) wv |= (__shfl(bi, tt*8) & 15) << (4*tt);
      if (lane == 0) bpw[t] = wv;
      float nfv = __shfl(nf, from*8);
      fv = v_from ? nfv : NEGV;
    }
  }
  // terminal: fv + trans[STOP][from]
  float bv = fv + (v_from ? trans[STOP_TAG*NTAGS + from] : -1e30f);
  int bi = from;
  #pragma unroll
  for (int d = 1; d < 8; d <<= 1){
    float ov = __shfl_xor(bv, d);
    int   oi = __shfl_xor(bi, d);
    if (ov > bv || (ov == bv && oi < bi)){ bv = ov; bi = oi; }
  }
  float score = __shfl(bv, 0);
  int btag = __shfl(bi, 0);
  if (lane == 0){ out[0] = score; out[TSEQ] = (float)btag; }   // out[1 + (T-1)]
  int tag = btag;
  for (int b = 63; b >= 0; b--){
    int v = bpw[b*64 + lane];
    for (int i = 63; i >= 0; i--){
      int t = b*64 + i;
      if (t == 0) break;                     // bpw[0] points at virtual START
      int wv2 = __shfl(v, i);
      int prev = (wv2 >> (tag*4)) & 15;
      if (lane == 0) out[t] = (float)prev;   // out[1 + (t-1)]
      tag = prev;
    }
  }
}

extern "C" void kernel_launch(void* const* d_in, const int* in_sizes, int n_in,
                              void* d_out, int out_size, void* d_ws, size_t ws_size,
                              hipStream_t stream) {
  const int*   sent = (const int*)  d_in[0];
  const float* emb  = (const float*)d_in[1];
  const float* Wihf = (const float*)d_in[2];
  const float* Whhf = (const float*)d_in[3];
  const float* bf_  = (const float*)d_in[4];
  const float* Wihb = (const float*)d_in[5];
  const float* Whhb = (const float*)d_in[6];
  const float* bb_  = (const float*)d_in[7];
  const float* Wout = (const float*)d_in[8];
  const float* bout = (const float*)d_in[9];
  const float* trans= (const float*)d_in[10];
  const float* h0   = (const float*)d_in[11];
  const float* c0   = (const float*)d_in[12];
  float* out = (float*)d_out;

  float* ws   = (float*)d_ws;
  float* A    = ws;                                  // [2][T][2048]
  float* hseq = A    + (size_t)2*TSEQ*NGATE;         // [2][T][512]
  u64*   mbox = (u64*)(hseq + (size_t)2*TSEQ*HH);    // [2][2][8][512] (tag,val)
  float* fe   = (float*)(mbox + (size_t)2*2*NREP*HH); // [T][8]
  int*   bpw  = (int*)(fe + (size_t)TSEQ*8);         // [T] packed nibbles
  (void)ws_size;

  k_init<<<(2*2*NREP*HH + 255)/256, 256, 0, stream>>>(h0, mbox);
  dim3 gg(TSEQ/128, 4096/128);
  k_inproj<<<gg, 256, 0, stream>>>(sent, emb, Wihf, bf_, Wihb, bb_, A);
  k_lstm<<<64, 512, 0, stream>>>(Whhf, Whhb, c0, A, hseq, mbox);
  k_feats<<<TSEQ, 64, 0, stream>>>(Wout, bout, hseq, fe);
  k_viterbi<<<1, 64, 0, stream>>>(trans, fe, bpw, out);
}